// Round 13
// baseline (604.003 us; speedup 1.0000x reference)
//
#include <hip/hip_runtime.h>
#include <hip/hip_bf16.h>

// DeepseekDecoderLayer on MI355X. Round 13: dual_all = r11 structure (BK=32,
// no swizzle — empirical best) + XCD-chunked mapping keyed on the SHARED A
// operand (h2b tokens). r12 post-mortem: swizzle killed all 6.1M bank
// conflicts but perf dropped -> conflicts weren't critical-path; BK=64 cost
// concurrency. dual is ~91% fetch-limited; ~90MB of its 330MB FETCH is h2b
// re-fetch across 22 n0-panels. Mapping xcd=bid%8 -> {3 sparse t's x 22
// panels + 1 shared rtile x 44 panels} makes A L2-resident per XCD while B
// stays uniquely streamed (dual of r8's failure: share the small resident
// operand, not the streaming one). down_all/QKV keep r12 (BK=64+swizzle,
// neutral-to-positive).

#define DI __device__ __forceinline__

typedef __attribute__((ext_vector_type(8))) short short8;
typedef __attribute__((ext_vector_type(4))) float f32x4;
using u16 = unsigned short;

struct alignas(8) U16x4 { u16 x, y, z, w; };

DI u16 f2bf(float f) {
  unsigned u = __float_as_uint(f);
  u += 0x7fffu + ((u >> 16) & 1u);
  return (u16)(u >> 16);
}
DI float bf2f(u16 h) { return __uint_as_float(((unsigned)h) << 16); }
// Packed round-half-up f32x2 -> bf16x2 (low half = f0). ~Nearest; bias ~2^-17.
DI unsigned pack2(float f0, float f1) {
  unsigned a = __float_as_uint(f0) + 0x8000u;
  unsigned b = __float_as_uint(f1) + 0x8000u;
  return (a >> 16) | (b & 0xffff0000u);
}

DI void gload16(const void* g, void* l) {
  __builtin_amdgcn_global_load_lds((const __attribute__((address_space(1))) void*)g,
                                   (__attribute__((address_space(3))) void*)l, 16, 0, 0);
}

// ---------------- small kernels ----------------

// RoPE cos/sin table in double precision (matches f64 numpy reference).
__global__ __launch_bounds__(256) void k_ropetab(float* __restrict__ tab) {
  int idx = blockIdx.x * 256 + threadIdx.x;  // < 1024*64
  int s = idx >> 6, i = idx & 63;
  double inv = pow(10000.0, -(double)(2 * i) / 128.0);
  double ang = (double)s * inv;
  tab[idx * 2 + 0] = (float)cos(ang);
  tab[idx * 2 + 1] = (float)sin(ang);
}

// RMSNorm row kernel: optional f32 out + optional bf16 hi/lo outs.
__global__ __launch_bounds__(256) void k_rmsnorm(const float* __restrict__ in,
                                                 const float* __restrict__ w,
                                                 float* __restrict__ outf,
                                                 u16* __restrict__ outh,
                                                 u16* __restrict__ outl) {
  const int row = blockIdx.x, t = threadIdx.x;
  const float* x = in + (size_t)row * 2048;
  float4 a = *(const float4*)&x[t * 4];
  float4 b = *(const float4*)&x[1024 + t * 4];
  float ss = a.x * a.x + a.y * a.y + a.z * a.z + a.w * a.w +
             b.x * b.x + b.y * b.y + b.z * b.z + b.w * b.w;
#pragma unroll
  for (int off = 32; off; off >>= 1) ss += __shfl_xor(ss, off);
  __shared__ float red[4];
  if ((t & 63) == 0) red[t >> 6] = ss;
  __syncthreads();
  float total = red[0] + red[1] + red[2] + red[3];
  float r = 1.0f / sqrtf(total * (1.0f / 2048.0f) + 1e-6f);
  float4 wa = *(const float4*)&w[t * 4];
  float4 wb = *(const float4*)&w[1024 + t * 4];
  float va[8] = {a.x * r * wa.x, a.y * r * wa.y, a.z * r * wa.z, a.w * r * wa.w,
                 b.x * r * wb.x, b.y * r * wb.y, b.z * r * wb.z, b.w * r * wb.w};
  if (outf) {
    *(float4*)&outf[(size_t)row * 2048 + t * 4] = make_float4(va[0], va[1], va[2], va[3]);
    *(float4*)&outf[(size_t)row * 2048 + 1024 + t * 4] = make_float4(va[4], va[5], va[6], va[7]);
  }
  if (outh) {
    U16x4 ha{f2bf(va[0]), f2bf(va[1]), f2bf(va[2]), f2bf(va[3])};
    U16x4 hb{f2bf(va[4]), f2bf(va[5]), f2bf(va[6]), f2bf(va[7])};
    *(U16x4*)&outh[(size_t)row * 2048 + t * 4] = ha;
    *(U16x4*)&outh[(size_t)row * 2048 + 1024 + t * 4] = hb;
    if (outl) {
      U16x4 la{f2bf(va[0] - bf2f(ha.x)), f2bf(va[1] - bf2f(ha.y)),
               f2bf(va[2] - bf2f(ha.z)), f2bf(va[3] - bf2f(ha.w))};
      U16x4 lb{f2bf(va[4] - bf2f(hb.x)), f2bf(va[5] - bf2f(hb.y)),
               f2bf(va[6] - bf2f(hb.z)), f2bf(va[7] - bf2f(hb.w))};
      *(U16x4*)&outl[(size_t)row * 2048 + t * 4] = la;
      *(U16x4*)&outl[(size_t)row * 2048 + 1024 + t * 4] = lb;
    }
  }
}

// Split 4 f32 arrays (each 4M elems) into bf16 hi/lo, one launch.
__global__ __launch_bounds__(256) void k_splitf4(
    const float* __restrict__ s0, const float* __restrict__ s1,
    const float* __restrict__ s2, const float* __restrict__ s3,
    u16* __restrict__ h0, u16* __restrict__ h1, u16* __restrict__ h2,
    u16* __restrict__ h3, u16* __restrict__ l0, u16* __restrict__ l1,
    u16* __restrict__ l2, u16* __restrict__ l3) {
  const int which = blockIdx.x >> 12;
  const int idx = ((blockIdx.x & 4095) * 256 + threadIdx.x) * 4;
  const float* src = (which == 0) ? s0 : (which == 1) ? s1 : (which == 2) ? s2 : s3;
  u16* dh = (which == 0) ? h0 : (which == 1) ? h1 : (which == 2) ? h2 : h3;
  u16* dl = (which == 0) ? l0 : (which == 1) ? l1 : (which == 2) ? l2 : l3;
  float4 v = *(const float4*)&src[idx];
  U16x4 h{f2bf(v.x), f2bf(v.y), f2bf(v.z), f2bf(v.w)};
  U16x4 l{f2bf(v.x - bf2f(h.x)), f2bf(v.y - bf2f(h.y)),
          f2bf(v.z - bf2f(h.z)), f2bf(v.w - bf2f(h.w))};
  *(U16x4*)&dh[idx] = h;
  *(U16x4*)&dl[idx] = l;
}

// Apply RoPE in-place to q (with 1/sqrt(128) folded in) and k. f32.
__global__ __launch_bounds__(256) void k_rope(float* __restrict__ q, float* __restrict__ k,
                                              const float* __restrict__ tab) {
  int idx = blockIdx.x * 256 + threadIdx.x;  // < 1024*16*64
  int s = idx >> 10, rem = idx & 1023;
  int h = rem >> 6, i = rem & 63;
  size_t base = (size_t)s * 2048 + h * 128 + i;
  float c = tab[(s * 64 + i) * 2 + 0];
  float sn = tab[(s * 64 + i) * 2 + 1];
  const float qs = 0.08838834764831845f;  // 1/sqrt(128)
  float q1 = q[base], q2 = q[base + 64];
  q[base] = (q1 * c - q2 * sn) * qs;
  q[base + 64] = (q2 * c + q1 * sn) * qs;
  float k1 = k[base], k2 = k[base + 64];
  k[base] = k1 * c - k2 * sn;
  k[base + 64] = k2 * c + k1 * sn;
}

// Split f32 q/k/v into bf16 hi/lo. Q,K keep [s][2048] layout; V transposed to
// [h*128+d][s].
__global__ __launch_bounds__(256) void k_splitkv(
    const float* __restrict__ qf, const float* __restrict__ kf,
    const float* __restrict__ vf,
    u16* __restrict__ Qh, u16* __restrict__ Ql,
    u16* __restrict__ Kh, u16* __restrict__ Kl,
    u16* __restrict__ Vth, u16* __restrict__ Vtl) {
  int idx = (blockIdx.x * 256 + threadIdx.x) * 4;  // over 1024*2048 elements
  int s = idx >> 11, c = idx & 2047;
  float4 q4 = *(const float4*)&qf[idx];
  U16x4 qh{f2bf(q4.x), f2bf(q4.y), f2bf(q4.z), f2bf(q4.w)};
  U16x4 ql{f2bf(q4.x - bf2f(qh.x)), f2bf(q4.y - bf2f(qh.y)),
           f2bf(q4.z - bf2f(qh.z)), f2bf(q4.w - bf2f(qh.w))};
  *(U16x4*)&Qh[idx] = qh; *(U16x4*)&Ql[idx] = ql;
  float4 k4 = *(const float4*)&kf[idx];
  U16x4 kh{f2bf(k4.x), f2bf(k4.y), f2bf(k4.z), f2bf(k4.w)};
  U16x4 kl{f2bf(k4.x - bf2f(kh.x)), f2bf(k4.y - bf2f(kh.y)),
           f2bf(k4.z - bf2f(kh.z)), f2bf(k4.w - bf2f(kh.w))};
  *(U16x4*)&Kh[idx] = kh; *(U16x4*)&Kl[idx] = kl;
  float4 v4 = *(const float4*)&vf[idx];
  float vv[4] = {v4.x, v4.y, v4.z, v4.w};
#pragma unroll
  for (int i = 0; i < 4; ++i) {
    u16 hv = f2bf(vv[i]);
    u16 lv = f2bf(vv[i] - bf2f(hv));
    Vth[(size_t)(c + i) * 1024 + s] = hv;
    Vtl[(size_t)(c + i) * 1024 + s] = lv;
  }
}

// ---------------- attention (LDS-staged, double-buffered) ----------------
DI void stage_kv(const u16* __restrict__ Khg, const u16* __restrict__ Klg,
                 const u16* __restrict__ Vhg, const u16* __restrict__ Vlg,
                 u16* lsKh, u16* lsKl, u16* lsVh, u16* lsVl,
                 int kvb, int hh, int wv, int lane) {
#pragma unroll
  for (int it = 0; it < 4; ++it) {
    const int ebase = it * 2048 + wv * 512;  // wave-uniform LDS base
    const int eo = ebase + lane * 8;
    {  // K tile [64 kv][128 d]
      const int rr = eo >> 7, cg = (eo >> 3) & 15;
      const size_t src = (size_t)(kvb + rr) * 2048 + hh * 128 + ((cg ^ (rr & 7)) << 3);
      gload16(Khg + src, lsKh + ebase);
      gload16(Klg + src, lsKl + ebase);
    }
    {  // V tile [128 d][64 kv]
      const int rr = eo >> 6, cg = (eo >> 3) & 7;
      const size_t src = (size_t)(hh * 128 + rr) * 1024 + kvb + ((cg ^ (rr & 7)) << 3);
      gload16(Vhg + src, lsVh + ebase);
      gload16(Vlg + src, lsVl + ebase);
    }
  }
}

__global__ __launch_bounds__(256) void k_attn_tile(
    const u16* __restrict__ Qh, const u16* __restrict__ Ql,
    const u16* __restrict__ Khg, const u16* __restrict__ Klg,
    const u16* __restrict__ Vhg, const u16* __restrict__ Vlg,
    u16* __restrict__ atth, u16* __restrict__ attl) {
  __shared__ u16 lsKh[2][8192], lsKl[2][8192], lsVh[2][8192], lsVl[2][8192];  // 128KB
  __shared__ u16 Plh[4][16][72], Pll[4][16][72];                              // 18KB
  const int hh = blockIdx.y;
  const int qb = blockIdx.x * 64;
  const int tid = threadIdx.x, lane = tid & 63, wv = tid >> 6;
  const int l15 = lane & 15, grp = lane >> 4;
  u16(*plh)[72] = Plh[wv];
  u16(*pll)[72] = Pll[wv];
  const int q_glob = qb + wv * 16 + l15;
  const int tend = blockIdx.x + 1;

  short8 qfh[4], qfl[4];
  const size_t qbase = (size_t)q_glob * 2048 + hh * 128;
#pragma unroll
  for (int c = 0; c < 4; ++c) {
    qfh[c] = *(const short8*)&Qh[qbase + c * 32 + grp * 8];
    qfl[c] = *(const short8*)&Ql[qbase + c * 32 + grp * 8];
  }
  f32x4 oacc[8];
#pragma unroll
  for (int dc = 0; dc < 8; ++dc) oacc[dc] = 0.f;
  float m_run = -1e30f, l_run = 0.f;

  int cur = 0;
  stage_kv(Khg, Klg, Vhg, Vlg, lsKh[0], lsKl[0], lsVh[0], lsVl[0], 0, hh, wv, lane);
  __syncthreads();

  for (int kt = 0; kt < tend; ++kt) {
    const int kvb = kt * 64;
    if (kt + 1 < tend)
      stage_kv(Khg, Klg, Vhg, Vlg, lsKh[cur ^ 1], lsKl[cur ^ 1], lsVh[cur ^ 1],
               lsVl[cur ^ 1], kvb + 64, hh, wv, lane);
    const u16* kh = lsKh[cur];
    const u16* kl = lsKl[cur];
    const u16* vh = lsVh[cur];
    const u16* vl = lsVl[cur];

    f32x4 s4[4];
#pragma unroll
    for (int sub = 0; sub < 4; ++sub) {
      f32x4 a = {0.f, 0.f, 0.f, 0.f};
      const int kr = sub * 16 + l15;
      const int sw = kr & 7;
#pragma unroll
      for (int c = 0; c < 4; ++c) {
        const int off = kr * 128 + ((((c << 2) | grp) ^ sw) << 3);
        short8 khf = *(const short8*)&kh[off];
        short8 klf = *(const short8*)&kl[off];
        a = __builtin_amdgcn_mfma_f32_16x16x32_bf16(khf, qfh[c], a, 0, 0, 0);
        a = __builtin_amdgcn_mfma_f32_16x16x32_bf16(klf, qfh[c], a, 0, 0, 0);
        a = __builtin_amdgcn_mfma_f32_16x16x32_bf16(khf, qfl[c], a, 0, 0, 0);
      }
      s4[sub] = a;
    }
    if (kt == tend - 1) {
#pragma unroll
      for (int sub = 0; sub < 4; ++sub)
#pragma unroll
        for (int r = 0; r < 4; ++r) {
          int kv = kvb + sub * 16 + grp * 4 + r;
          if (kv > q_glob) s4[sub][r] = -1e30f;
        }
    }
    float tmax = s4[0][0];
#pragma unroll
    for (int sub = 0; sub < 4; ++sub)
#pragma unroll
      for (int r = 0; r < 4; ++r) tmax = fmaxf(tmax, s4[sub][r]);
    tmax = fmaxf(tmax, __shfl_xor(tmax, 16));
    tmax = fmaxf(tmax, __shfl_xor(tmax, 32));
    float mnew = fmaxf(m_run, tmax);
    float scale = expf(m_run - mnew);
    float p[16], lsum = 0.f;
#pragma unroll
    for (int sub = 0; sub < 4; ++sub)
#pragma unroll
      for (int r = 0; r < 4; ++r) {
        float pe = expf(s4[sub][r] - mnew);
        p[sub * 4 + r] = pe;
        lsum += pe;
      }
    lsum += __shfl_xor(lsum, 16);
    lsum += __shfl_xor(lsum, 32);
    l_run = l_run * scale + lsum;
    m_run = mnew;
#pragma unroll
    for (int dc = 0; dc < 8; ++dc) oacc[dc] *= scale;
#pragma unroll
    for (int sub = 0; sub < 4; ++sub)
#pragma unroll
      for (int rp = 0; rp < 2; ++rp) {
        int i0 = sub * 4 + rp * 2;
        u16 h0 = f2bf(p[i0]), h1 = f2bf(p[i0 + 1]);
        u16 lo0 = f2bf(p[i0] - bf2f(h0)), lo1 = f2bf(p[i0 + 1] - bf2f(h1));
        int kvoff = sub * 16 + grp * 4 + rp * 2;
        *(unsigned*)&plh[l15][kvoff] = (unsigned)h0 | ((unsigned)h1 << 16);
        *(unsigned*)&pll[l15][kvoff] = (unsigned)lo0 | ((unsigned)lo1 << 16);
      }
    short8 phf[2], plf[2];
#pragma unroll
    for (int ks = 0; ks < 2; ++ks) {
      phf[ks] = *(const short8*)&plh[l15][ks * 32 + grp * 8];
      plf[ks] = *(const short8*)&pll[l15][ks * 32 + grp * 8];
    }
#pragma unroll
    for (int dc = 0; dc < 8; ++dc) {
      const int dr = dc * 16 + l15;
      const int sw = dr & 7;
      f32x4 acc = oacc[dc];
#pragma unroll
      for (int ks = 0; ks < 2; ++ks) {
        const int voff = dr * 64 + ((((ks << 2) | grp) ^ sw) << 3);
        short8 vhf = *(const short8*)&vh[voff];
        short8 vlf = *(const short8*)&vl[voff];
        acc = __builtin_amdgcn_mfma_f32_16x16x32_bf16(vhf, phf[ks], acc, 0, 0, 0);
        acc = __builtin_amdgcn_mfma_f32_16x16x32_bf16(vlf, phf[ks], acc, 0, 0, 0);
        acc = __builtin_amdgcn_mfma_f32_16x16x32_bf16(vhf, plf[ks], acc, 0, 0, 0);
      }
      oacc[dc] = acc;
    }
    __syncthreads();
    cur ^= 1;
  }
  float inv = 1.0f / l_run;
#pragma unroll
  for (int dc = 0; dc < 8; ++dc)
#pragma unroll
    for (int rp = 0; rp < 2; ++rp) {
      float v0 = oacc[dc][rp * 2] * inv;
      float v1 = oacc[dc][rp * 2 + 1] * inv;
      u16 h0 = f2bf(v0), h1 = f2bf(v1);
      u16 lo0 = f2bf(v0 - bf2f(h0)), lo1 = f2bf(v1 - bf2f(h1));
      size_t o = (size_t)q_glob * 2048 + hh * 128 + dc * 16 + grp * 4 + rp * 2;
      *(unsigned*)&atth[o] = (unsigned)h0 | ((unsigned)h1 << 16);
      *(unsigned*)&attl[o] = (unsigned)lo0 | ((unsigned)lo1 << 16);
    }
}

// Router: f32 logits (exact top-2 selection); emits top-2 idx + normed weights.
__global__ __launch_bounds__(256) void k_router(const float* __restrict__ h2f,
                                                const float* __restrict__ gw,
                                                int2* __restrict__ tidx,
                                                float2* __restrict__ twgt) {
  const int tok = blockIdx.x;
  const float* hrow = h2f + (size_t)tok * 2048;
  float part[8];
#pragma unroll
  for (int e = 0; e < 8; ++e) part[e] = 0.f;
  for (int j = 0; j < 8; ++j) {
    int p = j * 256 + threadIdx.x;
    float hv = hrow[p];
#pragma unroll
    for (int e = 0; e < 8; ++e) part[e] += hv * gw[e * 2048 + p];
  }
#pragma unroll
  for (int e = 0; e < 8; ++e)
#pragma unroll
    for (int off = 32; off; off >>= 1) part[e] += __shfl_xor(part[e], off);
  __shared__ float red[4][8];
  int wv = threadIdx.x >> 6, lane = threadIdx.x & 63;
  if (lane == 0) {
#pragma unroll
    for (int e = 0; e < 8; ++e) red[wv][e] = part[e];
  }
  __syncthreads();
  if (threadIdx.x == 0) {
    float lg[8];
#pragma unroll
    for (int e = 0; e < 8; ++e) lg[e] = red[0][e] + red[1][e] + red[2][e] + red[3][e];
    float m = lg[0];
#pragma unroll
    for (int e = 1; e < 8; ++e) m = fmaxf(m, lg[e]);
    float ex[8], s = 0.f;
#pragma unroll
    for (int e = 0; e < 8; ++e) { ex[e] = expf(lg[e] - m); s += ex[e]; }
#pragma unroll
    for (int e = 0; e < 8; ++e) ex[e] /= s;
    int i1 = 0;
#pragma unroll
    for (int e = 1; e < 8; ++e) if (ex[e] > ex[i1]) i1 = e;
    int i2 = (i1 == 0) ? 1 : 0;
#pragma unroll
    for (int e = 0; e < 8; ++e) if (e != i1 && ex[e] > ex[i2]) i2 = e;
    float s2 = ex[i1] + ex[i2] + 1e-20f;
    tidx[tok] = make_int2(i1, i2);
    twgt[tok] = make_float2(ex[i1] / s2, ex[i2] / s2);
  }
}

// Deterministic token gather, single wave (race-free). See r3 comments.
__global__ __launch_bounds__(64) void k_scan(const int2* __restrict__ tidx,
                                             const float2* __restrict__ twgt,
                                             int* __restrict__ meta,
                                             int* __restrict__ toklist,
                                             float* __restrict__ slotw,
                                             int* __restrict__ slots) {
  const int lane = threadIdx.x;
  int base = 0;
  for (int e = 0; e < 8; ++e) {
    int cnt = 0;
    for (int c = 0; c < 16; ++c) {
      const int tok = c * 64 + lane;
      int2 my = tidx[tok];
      int f1 = (my.x == e), f2 = (my.y == e);
      int flag = f1 | f2;
      unsigned long long m = __ballot(flag);
      if (flag) {
        float2 w = twgt[tok];
        int rank = (int)__popcll(m & ((1ull << lane) - 1ull));
        int s = base + cnt + rank;
        toklist[s] = tok;
        slotw[s] = f1 ? w.x : w.y;
        slots[tok * 2 + (f1 ? 0 : 1)] = s;
      }
      cnt += (int)__popcll(m);
    }
    if (lane == 0) { meta[e] = base; meta[9 + e] = cnt; }
    const int padded = ((cnt + 127) >> 7) << 7;
    for (int s = cnt + lane; s < padded; s += 64) {
      toklist[base + s] = 0;
      slotw[base + s] = 0.f;
    }
    base += padded;
  }
  if (lane == 0) meta[8] = base;
}

// ---------------- GEMM kernels ----------------
// C[M,N] = A[M,K] @ B[N,K]^T. MFMA 16x16x32 bf16; C/D: col=lane&15,
// row=(lane>>4)*4+reg.

// Split GEMM, all-bf16 staging, 128x64 tile, BK=64, swizzled (r12).
__global__ __launch_bounds__(256) void k_gemm_bf16split(
    const u16* __restrict__ Ah, const u16* __restrict__ Al,
    const u16* __restrict__ Bh0, const u16* __restrict__ Bl0,
    const u16* __restrict__ Bh1, const u16* __restrict__ Bl1,
    const u16* __restrict__ Bh2, const u16* __restrict__ Bl2,
    float* __restrict__ C0, float* __restrict__ C1, float* __restrict__ C2,
    const float* __restrict__ resid) {
  __shared__ u16 lsAh[8192], lsAl[8192], lsBh[4096], lsBl[4096];  // 48KB
  const int z = blockIdx.z;
  const u16* Bh = (z == 0) ? Bh0 : (z == 1) ? Bh1 : Bh2;
  const u16* Bl = (z == 0) ? Bl0 : (z == 1) ? Bl1 : Bl2;
  float* Cm = (z == 0) ? C0 : (z == 1) ? C1 : C2;
  const int tid = threadIdx.x, lane = tid & 63, wv = tid >> 6;
  const int wr = (wv >> 1) * 64, wc = (wv & 1) * 32;
  const int fr = lane & 15, fg = lane >> 4;
  const int row0 = blockIdx.x * 128, col0 = blockIdx.y * 64;
  f32x4 acc[4][2];
#pragma unroll
  for (int i = 0; i < 4; ++i)
#pragma unroll
    for (int j = 0; j < 2; ++j) acc[i][j] = 0.f;

  size_t aoff[4], boff[2];
#pragma unroll
  for (int it = 0; it < 4; ++it) {
    const int eo = it * 2048 + wv * 512 + lane * 8;
    const int r = eo >> 6, g = (eo >> 3) & 7;
    aoff[it] = (size_t)(row0 + r) * 2048 + ((g ^ (r & 7)) << 3);
  }
#pragma unroll
  for (int it = 0; it < 2; ++it) {
    const int eo = it * 2048 + wv * 512 + lane * 8;
    const int r = eo >> 6, g = (eo >> 3) & 7;
    boff[it] = (size_t)(col0 + r) * 2048 + ((g ^ (r & 7)) << 3);
  }

  for (int kt = 0; kt < 32; ++kt) {
    const int k0 = kt * 64;
#pragma unroll
    for (int it = 0; it < 4; ++it) {
      const int ebase = it * 2048 + wv * 512;
      gload16(Ah + aoff[it] + k0, lsAh + ebase);
      gload16(Al + aoff[it] + k0, lsAl + ebase);
    }
#pragma unroll
    for (int it = 0; it < 2; ++it) {
      const int ebase = it * 2048 + wv * 512;
      gload16(Bh + boff[it] + k0, lsBh + ebase);
      gload16(Bl + boff[it] + k0, lsBl + ebase);
    }
    __syncthreads();
#pragma unroll
    for (int kk = 0; kk < 2; ++kk) {
      short8 ah[4], al[4], bh[2], bl[2];
#pragma unroll
      for (int mi = 0; mi < 4; ++mi) {
        const int row = wr + mi * 16 + fr;
        const int off = row * 64 + ((kk * 32 + fg * 8) ^ ((row & 7) << 3));
        ah[mi] = *(const short8*)&lsAh[off];
        al[mi] = *(const short8*)&lsAl[off];
      }
#pragma unroll
      for (int ni = 0; ni < 2; ++ni) {
        const int row = wc + ni * 16 + fr;
        const int off = row * 64 + ((kk * 32 + fg * 8) ^ ((row & 7) << 3));
        bh[ni] = *(const short8*)&lsBh[off];
        bl[ni] = *(const short8*)&lsBl[off];
      }
#pragma unroll
      for (int mi = 0; mi < 4; ++mi)
#pragma unroll
        for (int ni = 0; ni < 2; ++ni) {
          f32x4 c = acc[mi][ni];
          c = __builtin_amdgcn_mfma_f32_16x16x32_bf16(al[mi], bh[ni], c, 0, 0, 0);
          c = __builtin_amdgcn_mfma_f32_16x16x32_bf16(ah[mi], bl[ni], c, 0, 0, 0);
          c = __builtin_amdgcn_mfma_f32_16x16x32_bf16(ah[mi], bh[ni], c, 0, 0, 0);
          acc[mi][ni] = c;
        }
    }
    __syncthreads();
  }
  const bool hasres = (resid != nullptr);
#pragma unroll
  for (int mi = 0; mi < 4; ++mi)
#pragma unroll
    for (int ni = 0; ni < 2; ++ni)
#pragma unroll
      for (int qq = 0; qq < 4; ++qq) {
        const int row = row0 + wr + mi * 16 + fg * 4 + qq;
        const int col = col0 + wc + ni * 16 + fr;
        float val = acc[mi][ni][qq];
        if (hasres) val += resid[(size_t)row * 2048 + col];
        Cm[(size_t)row * 2048 + col] = val;
      }
}

// Find expert for a padded row-tile index. meta[0..8] = offsets (mult of 128).
DI int tile_to_expert(const int* meta, int t) {
  int e = 0;
  while (e < 7 && t >= (meta[e + 1] >> 7)) ++e;
  return e;
}

// Fused dual GEMM + SiLU, r11 1-phase BK=32 structure + XCD-chunked mapping
// keyed on A: xcd=bid%8 owns tiles {c, c+8, c+16} x all 22 n0-panels (sparse)
// and shared rtile=c x 44 panels -> A stays L2-resident per XCD.
__global__ __launch_bounds__(256) void k_dual_all(
    const u16* __restrict__ h2b, const float* __restrict__ eg,
    const float* __restrict__ eu, const float* __restrict__ sg,
    const float* __restrict__ su, const int* __restrict__ meta,
    const int* __restrict__ toklist, const float* __restrict__ slotw,
    u16* __restrict__ act, u16* __restrict__ acts) {
  const int xcd = blockIdx.x & 7;
  const int i = blockIdx.x >> 3;  // 0..109
  const bool isShared = i >= 66;
  __shared__ int toks[128];
  __shared__ u16 lsA[4096], lsG[2048], lsU[2048];  // 16.5KB
  const int tid = threadIdx.x, lane = tid & 63, wv = tid >> 6;
  const int wr = (wv >> 1) * 64, wc = (wv & 1) * 32;
  const int fr = lane & 15, fg = lane >> 4;

  int n0, off_e = 0, cnt_e = 0, rtile = 0;
  const float *Bg, *Bu;
  if (isShared) {
    rtile = xcd;                 // 8 rtiles, one per XCD
    n0 = (i - 66) * 64;          // 44 panels
    Bg = sg;
    Bu = su;
    if (tid < 128) toks[tid] = rtile * 128 + tid;
  } else {
    const int t = xcd + 8 * (i / 22);  // tiles {xcd, xcd+8, xcd+16}
    n0 = (i % 22) * 64;
    if (t >= (meta[8] >> 7)) return;
    const int e = tile_to_expert(meta, t);
    off_e = meta[e];
    cnt_e = meta[9 + e];
    rtile = t - (off_e >> 7);
    Bg = eg + (size_t)e * 1408 * 2048;
    Bu = eu + (size_t)e * 1408 * 2048;
    if (tid < 128) toks[tid] = toklist[off_e + rtile * 128 + tid] & 1023;
  }
  f32x4 ag[4][2], au[4][2];
#pragma unroll
  for (int i2 = 0; i2 < 4; ++i2)
#pragma unroll
    for (int j = 0; j < 2; ++j) { ag[i2][j] = 0.f; au[i2][j] = 0.f; }
  __syncthreads();  // toks visible

  // Hoisted per-thread base addresses.
  const int ebase0 = wv * 512, ebase1 = 2048 + wv * 512;
  const int eoA0 = ebase0 + lane * 8, eoA1 = ebase1 + lane * 8;
  const u16* aS0 = h2b + (size_t)toks[eoA0 >> 5] * 2048 + (eoA0 & 31);
  const u16* aS1 = h2b + (size_t)toks[eoA1 >> 5] * 2048 + (eoA1 & 31);
  const int eoB0 = tid * 4, eoB1 = (256 + tid) * 4;
  const float* gB0 = Bg + (size_t)(n0 + (eoB0 >> 5)) * 2048 + (eoB0 & 31);
  const float* gB1 = Bg + (size_t)(n0 + (eoB1 >> 5)) * 2048 + (eoB1 & 31);
  const float* uB0 = Bu + (size_t)(n0 + (eoB0 >> 5)) * 2048 + (eoB0 & 31);
  const float* uB1 = Bu + (size_t)(n0 + (eoB1 >> 5)) * 2048 + (eoB1 & 31);

  for (int kt = 0; kt < 64; ++kt) {
    const int k0 = kt * 32;
    gload16(aS0 + k0, lsA + ebase0);
    gload16(aS1 + k0, lsA + ebase1);
    float4 g0 = *(const float4*)(gB0 + k0);
    float4 g1 = *(const float4*)(gB1 + k0);
    float4 u0 = *(const float4*)(uB0 + k0);
    float4 u1 = *(const float4*)(uB1 + k0);
    *(unsigned*)&lsG[eoB0] = pack2(g0.x, g0.y);
    *(unsigned*)&lsG[eoB0 + 2] = pack2(g0.z, g0.w);
    *(unsigned*)&lsG[eoB1] = pack2(g1.x, g1.y);
    *(unsigned*)&lsG[eoB1 + 2] = pack2(g1.z, g1.w);
    *(unsigned*)&lsU[eoB0] = pack2(u0.x, u0.y);
    *(unsigned*)&lsU[eoB0 + 2] = pack2(u0.z, u0.w);
    *(unsigned*)&lsU[eoB1] = pack2(u1.x, u1.y);
    *(unsigned*)&lsU[eoB1 + 2] = pack2(u1.z, u1.w);
    __syncthreads();
    short8 af[4], gf[2], uf[2];
#pragma unroll
    for (int mi = 0; mi < 4; ++mi)
      af[mi] = *(const short8*)&lsA[(wr + mi * 16 + fr) * 32 + fg * 8];
#pragma unroll
    for (int ni = 0; ni < 2; ++ni) {
      const int off = (wc + ni * 16 + fr) * 32 + fg * 8;
      gf[ni] = *(const short8*)&lsG[off];
      uf[ni] = *(const short8*)&lsU[off];
    }
#pragma unroll
    for (int mi = 0; mi < 4; ++mi)
#pragma unroll
      for (int ni = 0; ni < 2; ++ni) {
        ag[mi][ni] = __builtin_amdgcn_mfma_f32_16x16x32_bf16(af[mi], gf[ni], ag[mi][ni], 0, 0, 0);
        au[mi][ni] = __builtin_amdgcn_mfma_f32_16x16x32_bf16(af[mi], uf[ni], au[mi][ni], 0, 0, 0);
      }
    __syncthreads();
  }
#pragma unroll
  for (int mi = 0; mi < 4; ++mi)
#pragma unroll
    for (int ni = 0; ni < 2; ++ni)
#pragma unroll
      for (int qq = 0; qq < 4; ++qq) {
        const int r = wr + mi * 16 + fg * 4 + qq;
        const int col = n0 + wc + ni * 16 + fr;
        float g = ag[mi][ni][qq], u = au[mi][ni][qq];
        float a = g / (1.0f + expf(-g)) * u;
        if (isShared) {
          acts[(size_t)(rtile * 128 + r) * 2816 + col] = f2bf(a);
        } else {
          const int rowInE = rtile * 128 + r;
          if (rowInE < cnt_e)
            act[(size_t)(off_e + rowInE) * 1408 + col] = f2bf(a * slotw[off_e + rowInE]);
        }
      }
}

// Fused down GEMMs, r12 structure (BK=64, swizzled). Sparse (wid<384 -> dwn)
// + shared (wid>=384 -> shd).
__global__ __launch_bounds__(256) void k_down_all(
    const u16* __restrict__ act, const float* __restrict__ ed,
    const u16* __restrict__ acts, const float* __restrict__ sd,
    const int* __restrict__ meta, float* __restrict__ dwn,
    float* __restrict__ shd) {
  __shared__ u16 lsA[8192], lsB[8192];  // 32KB
  const int wid = blockIdx.x;
  const int tid = threadIdx.x, lane = tid & 63, wv = tid >> 6;
  const int fr = lane & 15, fg = lane >> 4;
  if (wid < 384) {
    const int t = wid >> 4;
    if (t >= (meta[8] >> 7)) return;
    const int col0 = (wid & 15) * 128;
    const int e = tile_to_expert(meta, t);
    const int off_e = meta[e];
    const int rtile = t - (off_e >> 7);
    const int wr = (wv >> 1) * 64, wc = (wv & 1) * 64;
    const u16* Ab = act + (size_t)off_e * 1408;
    const float* Bb = ed + (size_t)e * 2048 * 1408;
    const u16* aS[4];
#pragma unroll
    for (int it = 0; it < 4; ++it) {
      const int eo = it * 2048 + wv * 512 + lane * 8;
      const int r = eo >> 6, g = (eo >> 3) & 7;
      aS[it] = Ab + (size_t)(rtile * 128 + r) * 1408 + ((g ^ (r & 7)) << 3);
    }
    const float* bB[8];
    int sB[8];
#pragma unroll
    for (int j = 0; j < 8; ++j) {
      const int eo = (j * 256 + tid) * 4;
      const int row = eo >> 6, colu = eo & 63;
      sB[j] = row * 64 + (colu ^ ((row & 7) << 3));
      bB[j] = Bb + (size_t)(col0 + row) * 1408 + colu;
    }
    f32x4 acc[4][4];
#pragma unroll
    for (int i = 0; i < 4; ++i)
#pragma unroll
      for (int j = 0; j < 4; ++j) acc[i][j] = 0.f;
    for (int kt = 0; kt < 22; ++kt) {
      const int k0 = kt * 64;
#pragma unroll
      for (int it = 0; it < 4; ++it)
        gload16(aS[it] + k0, lsA + it * 2048 + wv * 512);
#pragma unroll
      for (int j = 0; j < 8; ++j) {
        float4 b = *(const float4*)(bB[j] + k0);
        *(unsigned*)&lsB[sB[j]] = pack2(b.x, b.y);
        *(unsigned*)&lsB[sB[j] + 2] = pack2(b.z, b.w);
      }
      __syncthreads();
#pragma unroll
      for (int kk = 0; kk < 2; ++kk) {
        short8 af[4], bf_[4];
#pragma unroll
        for (int mi = 0; mi < 4; ++mi) {
          const int row = wr + mi * 16 + fr;
          af[mi] = *(const short8*)&lsA[row * 64 + ((kk * 32 + fg * 8) ^ ((row & 7) << 3))];
        }
#pragma unroll
        for (int ni = 0; ni < 4; ++ni) {
          const int row = wc + ni * 16 + fr;
          bf_[ni] = *(const short8*)&lsB[row * 64 + ((kk * 32 + fg * 8) ^ ((row & 7) << 3))];
        }
#pragma unroll
        for (int mi = 0; mi < 4; ++mi)
#pragma unroll
          for (int ni = 0; ni < 4; ++ni)
            acc[mi][ni] = __builtin_amdgcn_mfma_f32_16x16x32_bf16(af[mi], bf_[ni], acc[mi][ni], 0, 0, 0);
      }
      __syncthreads();
    }
#pragma unroll
    for (int mi = 0; mi < 4; ++mi)
#pragma unroll
      for (int ni = 0; ni < 4; ++ni)
#pragma unroll
        for (int qq = 0; qq < 4; ++qq) {
          const int r = wr + mi * 16 + fg * 4 + qq;
          const int col = col0 + wc + ni * 16 + fr;
          dwn[(size_t)(off_e + rtile * 128 + r) * 2048 + col] = acc[mi][ni][qq];
        }
  } else {
    const int b2 = wid - 384;
    const int row0 = (b2 >> 5) * 128;
    const int col0 = (b2 & 31) * 64;
    const int wr = (wv >> 1) * 64, wc = (wv & 1) * 32;
    const u16* aS[4];
#pragma unroll
    for (int it = 0; it < 4; ++it) {
      const int eo = it * 2048 + wv * 512 + lane * 8;
      const int r = eo >> 6, g = (eo >> 3) & 7;
      aS[it] = acts + (size_t)(row0 + r) * 2816 + ((g ^ (r & 7)) << 3);
    }
    const float* bB[4];
    int sB[4];
#pragma unroll
    for (int j = 0; j < 4; ++j) {
      const int eo = (j * 256 + tid) * 4;
      const int row = eo >> 6, colu = eo & 63;
      sB[j] = row * 64 + (colu ^ ((row & 7) << 3));
      bB[j] = sd + (size_t)(col0 + row) * 2816 + colu;
    }
    f32x4 acc[4][2];
#pragma unroll
    for (int i = 0; i < 4; ++i)
#pragma unroll
      for (int j = 0; j < 2; ++j) acc[i][j] = 0.f;
    for (int kt = 0; kt < 44; ++kt) {
      const int k0 = kt * 64;
#pragma unroll
      for (int it = 0; it < 4; ++it)
        gload16(aS[it] + k0, lsA + it * 2048 + wv * 512);
#pragma unroll
      for (int j = 0; j < 4; ++j) {
        float4 b = *(const float4*)(bB[j] + k0);
        *(unsigned*)&lsB[sB[j]] = pack2(b.x, b.y);
        *(unsigned*)&lsB[sB[j] + 2] = pack2(b.z, b.w);
      }
      __syncthreads();
#pragma unroll
      for (int kk = 0; kk < 2; ++kk) {
        short8 af[4], bf_[2];
#pragma unroll
        for (int mi = 0; mi < 4; ++mi) {
          const int row = wr + mi * 16 + fr;
          af[mi] = *(const short8*)&lsA[row * 64 + ((kk * 32 + fg * 8) ^ ((row & 7) << 3))];
        }
#pragma unroll
        for (int ni = 0; ni < 2; ++ni) {
          const int row = wc + ni * 16 + fr;
          bf_[ni] = *(const short8*)&lsB[row * 64 + ((kk * 32 + fg * 8) ^ ((row & 7) << 3))];
        }
#pragma unroll
        for (int mi = 0; mi < 4; ++mi)
#pragma unroll
          for (int ni = 0; ni < 2; ++ni)
            acc[mi][ni] = __builtin_amdgcn_mfma_f32_16x16x32_bf16(af[mi], bf_[ni], acc[mi][ni], 0, 0, 0);
      }
      __syncthreads();
    }
#pragma unroll
    for (int mi = 0; mi < 4; ++mi)
#pragma unroll
      for (int ni = 0; ni < 2; ++ni)
#pragma unroll
        for (int qq = 0; qq < 4; ++qq) {
          const int row = row0 + wr + mi * 16 + fg * 4 + qq;
          const int col = col0 + wc + ni * 16 + fr;
          shd[(size_t)row * 2048 + col] = acc[mi][ni][qq];
        }
  }
}

// Final combine: out = x + shd + dwn[slot0] + dwn[slot1].
__global__ __launch_bounds__(256) void k_combine(
    const float* __restrict__ shd, const float* __restrict__ x,
    const float* __restrict__ dwn, const int* __restrict__ slots,
    float* __restrict__ outp) {
  const int i4 = (blockIdx.x * 256 + threadIdx.x) * 4;
  const int row = i4 >> 11, col = i4 & 2047;
  const int s0 = slots[row * 2], s1 = slots[row * 2 + 1];
  float4 a = *(const float4*)&shd[i4];
  float4 b = *(const float4*)&x[i4];
  float4 c = *(const float4*)&dwn[(size_t)s0 * 2048 + col];
  float4 d = *(const float4*)&dwn[(size_t)s1 * 2048 + col];
  float4 o;
  o.x = a.x + b.x + c.x + d.x;
  o.y = a.y + b.y + c.y + d.y;
  o.z = a.z + b.z + c.z + d.z;
  o.w = a.w + b.w + c.w + d.w;
  *(float4*)&outp[i4] = o;
}

// ---------------- host launch ----------------

extern "C" void kernel_launch(void* const* d_in, const int* in_sizes, int n_in,
                              void* d_out, int out_size, void* d_ws, size_t ws_size,
                              hipStream_t stream) {
  (void)in_sizes; (void)n_in; (void)out_size; (void)ws_size;
  const float* hidden = (const float*)d_in[0];
  const float* ln1 = (const float*)d_in[1];
  const float* ln2 = (const float*)d_in[2];
  const float* wq = (const float*)d_in[3];
  const float* wk = (const float*)d_in[4];
  const float* wvw = (const float*)d_in[5];
  const float* wo = (const float*)d_in[6];
  const float* gw = (const float*)d_in[7];
  const float* eg = (const float*)d_in[8];
  const float* eu = (const float*)d_in[9];
  const float* ed = (const float*)d_in[10];
  const float* sg = (const float*)d_in[11];
  const float* su = (const float*)d_in[12];
  const float* sd = (const float*)d_in[13];
  float* out = (float*)d_out;
  char* ws = (char*)d_ws;

  const size_t KB = 1ull << 10, MB = 1ull << 20;
  float* tab = (float*)(ws + 0);             // [0, 0.5MB)
  int2* tidx = (int2*)(ws + 512 * KB);
  float2* twgt = (float2*)(ws + 520 * KB);
  int* meta = (int*)(ws + 528 * KB);
  int* tokl = (int*)(ws + 532 * KB);
  float* slw = (float*)(ws + 544 * KB);
  int* slots = (int*)(ws + 556 * KB);
  u16* hnh = (u16*)(ws + 1 * MB);            // [1,5)   dies after QKV
  u16* hnl = (u16*)(ws + 5 * MB);            // [5,9)
  u16* wqh = (u16*)(ws + 9 * MB);            // [9,57): split wq/wk/wv, die after QKV
  u16* wql = (u16*)(ws + 17 * MB);
  u16* wkh = (u16*)(ws + 25 * MB);
  u16* wkl = (u16*)(ws + 33 * MB);
  u16* wvh = (u16*)(ws + 41 * MB);
  u16* wvl = (u16*)(ws + 49 * MB);
  u16* woh = (u16*)(ws + 57 * MB);           // [57,73): dies after O-proj
  u16* wol = (u16*)(ws + 65 * MB);
  float* qf = (float*)(ws + 73 * MB);        // [73,81) dies after splitkv
  float* kf = (float*)(ws + 81 * MB);        // [81,89)
  float* vf = (float*)(ws + 89 * MB);        // [89,97)
  // After QKV GEMM (wq..wvl dead):
  u16* Qh = (u16*)(ws + 9 * MB);             // [9,33): attn operands
  u16* Ql = (u16*)(ws + 13 * MB);
  u16* Kh = (u16*)(ws + 17 * MB);
  u16* Kl = (u16*)(ws + 21 * MB);
  u16* Vth = (u16*)(ws + 25 * MB);
  u16* Vtl = (u16*)(ws + 29 * MB);
  u16* atth = (u16*)(ws + 33 * MB);          // [33,41): dies after O-proj
  u16* attl = (u16*)(ws + 37 * MB);
  float* xf = (float*)(ws + 41 * MB);        // [41,49): residual2 (live to end)
  float* h2f = (float*)(ws + 49 * MB);       // [49,57)
  u16* h2b = (u16*)(ws + 1 * MB);            // [1,5) (hnh dead)
  // MoE (after attn; Qh..Vtl / qf..vf / atth dead):
  u16* act = (u16*)(ws + 73 * MB);           // [73,82)  3072x1408 bf16
  u16* acts = (u16*)(ws + 82 * MB);          // [82,88)  1024x2816 bf16
  float* dwn = (float*)(ws + 9 * MB);        // [9,33)   3072x2048 f32
  float* shd = (float*)(ws + 33 * MB);       // [33,41)  1024x2048 f32

  k_ropetab<<<256, 256, 0, stream>>>(tab);
  k_rmsnorm<<<1024, 256, 0, stream>>>(hidden, ln1, nullptr, hnh, hnl);
  k_splitf4<<<16384, 256, 0, stream>>>(wq, wk, wvw, wo, wqh, wkh, wvh, woh,
                                       wql, wkl, wvl, wol);
  k_gemm_bf16split<<<dim3(8, 32, 3), 256, 0, stream>>>(
      hnh, hnl, wqh, wql, wkh, wkl, wvh, wvl, qf, kf, vf, nullptr);
  k_rope<<<4096, 256, 0, stream>>>(qf, kf, tab);
  k_splitkv<<<2048, 256, 0, stream>>>(qf, kf, vf, Qh, Ql, Kh, Kl, Vth, Vtl);
  k_attn_tile<<<dim3(16, 16), 256, 0, stream>>>(Qh, Ql, Kh, Kl, Vth, Vtl, atth, attl);
  k_gemm_bf16split<<<dim3(8, 32, 1), 256, 0, stream>>>(
      atth, attl, woh, wol, woh, wol, woh, wol, xf, xf, xf, hidden);
  k_rmsnorm<<<1024, 256, 0, stream>>>(xf, ln2, h2f, h2b, nullptr);
  k_router<<<1024, 256, 0, stream>>>(h2f, gw, tidx, twgt);
  k_scan<<<1, 64, 0, stream>>>(tidx, twgt, meta, tokl, slw, slots);
  k_dual_all<<<880, 256, 0, stream>>>(h2b, eg, eu, sg, su, meta, tokl, slw, act, acts);
  k_down_all<<<640, 256, 0, stream>>>(act, ed, acts, sd, meta, dwn, shd);
  k_combine<<<2048, 256, 0, stream>>>(shd, xf, dwn, slots, out);
}

// Round 14
// 533.698 us; speedup vs baseline: 1.1317x; 1.1317x over previous
//
#include <hip/hip_runtime.h>
#include <hip/hip_bf16.h>

// DeepseekDecoderLayer on MI355X. Round 14: freeze MoE at the settled optimum.
// r13 post-mortem: XCD-keyed mapping RAISED fetch (330->390MB) — r11's
// t-major order had hidden B-panel L2 locality (consecutive blocks stream the
// same expert). After 2 failed reorderings + 2 failed pipelines, r11's dual
// (129us, 2.8TB/s, fetch-limited) is the local optimum; reverted exactly.
// down_all/QKV keep r12 (BK=64+swizzle, neutral-positive). New: RoPE fused
// into the Q/K hi/lo split (k_ropesplit) — removes the separate in-place rope
// pass (-32MB traffic, -1 launch). V split unchanged (k_splitv).

#define DI __device__ __forceinline__

typedef __attribute__((ext_vector_type(8))) short short8;
typedef __attribute__((ext_vector_type(4))) float f32x4;
using u16 = unsigned short;

struct alignas(8) U16x4 { u16 x, y, z, w; };

DI u16 f2bf(float f) {
  unsigned u = __float_as_uint(f);
  u += 0x7fffu + ((u >> 16) & 1u);
  return (u16)(u >> 16);
}
DI float bf2f(u16 h) { return __uint_as_float(((unsigned)h) << 16); }
// Packed round-half-up f32x2 -> bf16x2 (low half = f0). ~Nearest; bias ~2^-17.
DI unsigned pack2(float f0, float f1) {
  unsigned a = __float_as_uint(f0) + 0x8000u;
  unsigned b = __float_as_uint(f1) + 0x8000u;
  return (a >> 16) | (b & 0xffff0000u);
}

DI void gload16(const void* g, void* l) {
  __builtin_amdgcn_global_load_lds((const __attribute__((address_space(1))) void*)g,
                                   (__attribute__((address_space(3))) void*)l, 16, 0, 0);
}

// ---------------- small kernels ----------------

// RoPE cos/sin table in double precision (matches f64 numpy reference).
__global__ __launch_bounds__(256) void k_ropetab(float* __restrict__ tab) {
  int idx = blockIdx.x * 256 + threadIdx.x;  // < 1024*64
  int s = idx >> 6, i = idx & 63;
  double inv = pow(10000.0, -(double)(2 * i) / 128.0);
  double ang = (double)s * inv;
  tab[idx * 2 + 0] = (float)cos(ang);
  tab[idx * 2 + 1] = (float)sin(ang);
}

// RMSNorm row kernel: optional f32 out + optional bf16 hi/lo outs.
__global__ __launch_bounds__(256) void k_rmsnorm(const float* __restrict__ in,
                                                 const float* __restrict__ w,
                                                 float* __restrict__ outf,
                                                 u16* __restrict__ outh,
                                                 u16* __restrict__ outl) {
  const int row = blockIdx.x, t = threadIdx.x;
  const float* x = in + (size_t)row * 2048;
  float4 a = *(const float4*)&x[t * 4];
  float4 b = *(const float4*)&x[1024 + t * 4];
  float ss = a.x * a.x + a.y * a.y + a.z * a.z + a.w * a.w +
             b.x * b.x + b.y * b.y + b.z * b.z + b.w * b.w;
#pragma unroll
  for (int off = 32; off; off >>= 1) ss += __shfl_xor(ss, off);
  __shared__ float red[4];
  if ((t & 63) == 0) red[t >> 6] = ss;
  __syncthreads();
  float total = red[0] + red[1] + red[2] + red[3];
  float r = 1.0f / sqrtf(total * (1.0f / 2048.0f) + 1e-6f);
  float4 wa = *(const float4*)&w[t * 4];
  float4 wb = *(const float4*)&w[1024 + t * 4];
  float va[8] = {a.x * r * wa.x, a.y * r * wa.y, a.z * r * wa.z, a.w * r * wa.w,
                 b.x * r * wb.x, b.y * r * wb.y, b.z * r * wb.z, b.w * r * wb.w};
  if (outf) {
    *(float4*)&outf[(size_t)row * 2048 + t * 4] = make_float4(va[0], va[1], va[2], va[3]);
    *(float4*)&outf[(size_t)row * 2048 + 1024 + t * 4] = make_float4(va[4], va[5], va[6], va[7]);
  }
  if (outh) {
    U16x4 ha{f2bf(va[0]), f2bf(va[1]), f2bf(va[2]), f2bf(va[3])};
    U16x4 hb{f2bf(va[4]), f2bf(va[5]), f2bf(va[6]), f2bf(va[7])};
    *(U16x4*)&outh[(size_t)row * 2048 + t * 4] = ha;
    *(U16x4*)&outh[(size_t)row * 2048 + 1024 + t * 4] = hb;
    if (outl) {
      U16x4 la{f2bf(va[0] - bf2f(ha.x)), f2bf(va[1] - bf2f(ha.y)),
               f2bf(va[2] - bf2f(ha.z)), f2bf(va[3] - bf2f(ha.w))};
      U16x4 lb{f2bf(va[4] - bf2f(hb.x)), f2bf(va[5] - bf2f(hb.y)),
               f2bf(va[6] - bf2f(hb.z)), f2bf(va[7] - bf2f(hb.w))};
      *(U16x4*)&outl[(size_t)row * 2048 + t * 4] = la;
      *(U16x4*)&outl[(size_t)row * 2048 + 1024 + t * 4] = lb;
    }
  }
}

// Split 4 f32 arrays (each 4M elems) into bf16 hi/lo, one launch.
__global__ __launch_bounds__(256) void k_splitf4(
    const float* __restrict__ s0, const float* __restrict__ s1,
    const float* __restrict__ s2, const float* __restrict__ s3,
    u16* __restrict__ h0, u16* __restrict__ h1, u16* __restrict__ h2,
    u16* __restrict__ h3, u16* __restrict__ l0, u16* __restrict__ l1,
    u16* __restrict__ l2, u16* __restrict__ l3) {
  const int which = blockIdx.x >> 12;
  const int idx = ((blockIdx.x & 4095) * 256 + threadIdx.x) * 4;
  const float* src = (which == 0) ? s0 : (which == 1) ? s1 : (which == 2) ? s2 : s3;
  u16* dh = (which == 0) ? h0 : (which == 1) ? h1 : (which == 2) ? h2 : h3;
  u16* dl = (which == 0) ? l0 : (which == 1) ? l1 : (which == 2) ? l2 : l3;
  float4 v = *(const float4*)&src[idx];
  U16x4 h{f2bf(v.x), f2bf(v.y), f2bf(v.z), f2bf(v.w)};
  U16x4 l{f2bf(v.x - bf2f(h.x)), f2bf(v.y - bf2f(h.y)),
          f2bf(v.z - bf2f(h.z)), f2bf(v.w - bf2f(h.w))};
  *(U16x4*)&dh[idx] = h;
  *(U16x4*)&dl[idx] = l;
}

// Fused RoPE + hi/lo split for Q (with 1/sqrt(128) folded) and K.
// Thread handles 4 i-positions of one (s,h): elements i and i+64.
__global__ __launch_bounds__(256) void k_ropesplit(
    const float* __restrict__ qf, const float* __restrict__ kf,
    const float* __restrict__ tab,
    u16* __restrict__ Qh, u16* __restrict__ Ql,
    u16* __restrict__ Kh, u16* __restrict__ Kl) {
  const int idx = blockIdx.x * 256 + threadIdx.x;  // < 1024*16*16
  const int s = idx >> 8, rem = idx & 255;
  const int h = rem >> 4, i = (rem & 15) * 4;
  const size_t base = (size_t)s * 2048 + h * 128 + i;
  const float qs = 0.08838834764831845f;  // 1/sqrt(128)
  float4 t0 = *(const float4*)&tab[(s * 64 + i) * 2];      // c0 s0 c1 s1
  float4 t1 = *(const float4*)&tab[(s * 64 + i) * 2 + 4];  // c2 s2 c3 s3
  float c[4] = {t0.x, t0.z, t1.x, t1.z};
  float sn[4] = {t0.y, t0.w, t1.y, t1.w};
  float4 q1 = *(const float4*)&qf[base];
  float4 q2 = *(const float4*)&qf[base + 64];
  float4 k1 = *(const float4*)&kf[base];
  float4 k2 = *(const float4*)&kf[base + 64];
  float q1v[4] = {q1.x, q1.y, q1.z, q1.w}, q2v[4] = {q2.x, q2.y, q2.z, q2.w};
  float k1v[4] = {k1.x, k1.y, k1.z, k1.w}, k2v[4] = {k2.x, k2.y, k2.z, k2.w};
  U16x4 qh1, ql1, qh2, ql2, kh1, kl1, kh2, kl2;
  u16 *qh1p = &qh1.x, *ql1p = &ql1.x, *qh2p = &qh2.x, *ql2p = &ql2.x;
  u16 *kh1p = &kh1.x, *kl1p = &kl1.x, *kh2p = &kh2.x, *kl2p = &kl2.x;
#pragma unroll
  for (int j = 0; j < 4; ++j) {
    float a = (q1v[j] * c[j] - q2v[j] * sn[j]) * qs;
    float b = (q2v[j] * c[j] + q1v[j] * sn[j]) * qs;
    u16 ah = f2bf(a), bh = f2bf(b);
    qh1p[j] = ah; ql1p[j] = f2bf(a - bf2f(ah));
    qh2p[j] = bh; ql2p[j] = f2bf(b - bf2f(bh));
    float ka = k1v[j] * c[j] - k2v[j] * sn[j];
    float kb = k2v[j] * c[j] + k1v[j] * sn[j];
    u16 kah = f2bf(ka), kbh = f2bf(kb);
    kh1p[j] = kah; kl1p[j] = f2bf(ka - bf2f(kah));
    kh2p[j] = kbh; kl2p[j] = f2bf(kb - bf2f(kbh));
  }
  *(U16x4*)&Qh[base] = qh1; *(U16x4*)&Ql[base] = ql1;
  *(U16x4*)&Qh[base + 64] = qh2; *(U16x4*)&Ql[base + 64] = ql2;
  *(U16x4*)&Kh[base] = kh1; *(U16x4*)&Kl[base] = kl1;
  *(U16x4*)&Kh[base + 64] = kh2; *(U16x4*)&Kl[base + 64] = kl2;
}

// Split f32 v into bf16 hi/lo, transposed to [h*128+d][s].
__global__ __launch_bounds__(256) void k_splitv(
    const float* __restrict__ vf, u16* __restrict__ Vth, u16* __restrict__ Vtl) {
  int idx = (blockIdx.x * 256 + threadIdx.x) * 4;  // over 1024*2048 elements
  int s = idx >> 11, c = idx & 2047;
  float4 v4 = *(const float4*)&vf[idx];
  float vv[4] = {v4.x, v4.y, v4.z, v4.w};
#pragma unroll
  for (int i = 0; i < 4; ++i) {
    u16 hv = f2bf(vv[i]);
    u16 lv = f2bf(vv[i] - bf2f(hv));
    Vth[(size_t)(c + i) * 1024 + s] = hv;
    Vtl[(size_t)(c + i) * 1024 + s] = lv;
  }
}

// ---------------- attention (LDS-staged, double-buffered) ----------------
DI void stage_kv(const u16* __restrict__ Khg, const u16* __restrict__ Klg,
                 const u16* __restrict__ Vhg, const u16* __restrict__ Vlg,
                 u16* lsKh, u16* lsKl, u16* lsVh, u16* lsVl,
                 int kvb, int hh, int wv, int lane) {
#pragma unroll
  for (int it = 0; it < 4; ++it) {
    const int ebase = it * 2048 + wv * 512;  // wave-uniform LDS base
    const int eo = ebase + lane * 8;
    {  // K tile [64 kv][128 d]
      const int rr = eo >> 7, cg = (eo >> 3) & 15;
      const size_t src = (size_t)(kvb + rr) * 2048 + hh * 128 + ((cg ^ (rr & 7)) << 3);
      gload16(Khg + src, lsKh + ebase);
      gload16(Klg + src, lsKl + ebase);
    }
    {  // V tile [128 d][64 kv]
      const int rr = eo >> 6, cg = (eo >> 3) & 7;
      const size_t src = (size_t)(hh * 128 + rr) * 1024 + kvb + ((cg ^ (rr & 7)) << 3);
      gload16(Vhg + src, lsVh + ebase);
      gload16(Vlg + src, lsVl + ebase);
    }
  }
}

__global__ __launch_bounds__(256) void k_attn_tile(
    const u16* __restrict__ Qh, const u16* __restrict__ Ql,
    const u16* __restrict__ Khg, const u16* __restrict__ Klg,
    const u16* __restrict__ Vhg, const u16* __restrict__ Vlg,
    u16* __restrict__ atth, u16* __restrict__ attl) {
  __shared__ u16 lsKh[2][8192], lsKl[2][8192], lsVh[2][8192], lsVl[2][8192];  // 128KB
  __shared__ u16 Plh[4][16][72], Pll[4][16][72];                              // 18KB
  const int hh = blockIdx.y;
  const int qb = blockIdx.x * 64;
  const int tid = threadIdx.x, lane = tid & 63, wv = tid >> 6;
  const int l15 = lane & 15, grp = lane >> 4;
  u16(*plh)[72] = Plh[wv];
  u16(*pll)[72] = Pll[wv];
  const int q_glob = qb + wv * 16 + l15;
  const int tend = blockIdx.x + 1;

  short8 qfh[4], qfl[4];
  const size_t qbase = (size_t)q_glob * 2048 + hh * 128;
#pragma unroll
  for (int c = 0; c < 4; ++c) {
    qfh[c] = *(const short8*)&Qh[qbase + c * 32 + grp * 8];
    qfl[c] = *(const short8*)&Ql[qbase + c * 32 + grp * 8];
  }
  f32x4 oacc[8];
#pragma unroll
  for (int dc = 0; dc < 8; ++dc) oacc[dc] = 0.f;
  float m_run = -1e30f, l_run = 0.f;

  int cur = 0;
  stage_kv(Khg, Klg, Vhg, Vlg, lsKh[0], lsKl[0], lsVh[0], lsVl[0], 0, hh, wv, lane);
  __syncthreads();

  for (int kt = 0; kt < tend; ++kt) {
    const int kvb = kt * 64;
    if (kt + 1 < tend)
      stage_kv(Khg, Klg, Vhg, Vlg, lsKh[cur ^ 1], lsKl[cur ^ 1], lsVh[cur ^ 1],
               lsVl[cur ^ 1], kvb + 64, hh, wv, lane);
    const u16* kh = lsKh[cur];
    const u16* kl = lsKl[cur];
    const u16* vh = lsVh[cur];
    const u16* vl = lsVl[cur];

    f32x4 s4[4];
#pragma unroll
    for (int sub = 0; sub < 4; ++sub) {
      f32x4 a = {0.f, 0.f, 0.f, 0.f};
      const int kr = sub * 16 + l15;
      const int sw = kr & 7;
#pragma unroll
      for (int c = 0; c < 4; ++c) {
        const int off = kr * 128 + ((((c << 2) | grp) ^ sw) << 3);
        short8 khf = *(const short8*)&kh[off];
        short8 klf = *(const short8*)&kl[off];
        a = __builtin_amdgcn_mfma_f32_16x16x32_bf16(khf, qfh[c], a, 0, 0, 0);
        a = __builtin_amdgcn_mfma_f32_16x16x32_bf16(klf, qfh[c], a, 0, 0, 0);
        a = __builtin_amdgcn_mfma_f32_16x16x32_bf16(khf, qfl[c], a, 0, 0, 0);
      }
      s4[sub] = a;
    }
    if (kt == tend - 1) {
#pragma unroll
      for (int sub = 0; sub < 4; ++sub)
#pragma unroll
        for (int r = 0; r < 4; ++r) {
          int kv = kvb + sub * 16 + grp * 4 + r;
          if (kv > q_glob) s4[sub][r] = -1e30f;
        }
    }
    float tmax = s4[0][0];
#pragma unroll
    for (int sub = 0; sub < 4; ++sub)
#pragma unroll
      for (int r = 0; r < 4; ++r) tmax = fmaxf(tmax, s4[sub][r]);
    tmax = fmaxf(tmax, __shfl_xor(tmax, 16));
    tmax = fmaxf(tmax, __shfl_xor(tmax, 32));
    float mnew = fmaxf(m_run, tmax);
    float scale = expf(m_run - mnew);
    float p[16], lsum = 0.f;
#pragma unroll
    for (int sub = 0; sub < 4; ++sub)
#pragma unroll
      for (int r = 0; r < 4; ++r) {
        float pe = expf(s4[sub][r] - mnew);
        p[sub * 4 + r] = pe;
        lsum += pe;
      }
    lsum += __shfl_xor(lsum, 16);
    lsum += __shfl_xor(lsum, 32);
    l_run = l_run * scale + lsum;
    m_run = mnew;
#pragma unroll
    for (int dc = 0; dc < 8; ++dc) oacc[dc] *= scale;
#pragma unroll
    for (int sub = 0; sub < 4; ++sub)
#pragma unroll
      for (int rp = 0; rp < 2; ++rp) {
        int i0 = sub * 4 + rp * 2;
        u16 h0 = f2bf(p[i0]), h1 = f2bf(p[i0 + 1]);
        u16 lo0 = f2bf(p[i0] - bf2f(h0)), lo1 = f2bf(p[i0 + 1] - bf2f(h1));
        int kvoff = sub * 16 + grp * 4 + rp * 2;
        *(unsigned*)&plh[l15][kvoff] = (unsigned)h0 | ((unsigned)h1 << 16);
        *(unsigned*)&pll[l15][kvoff] = (unsigned)lo0 | ((unsigned)lo1 << 16);
      }
    short8 phf[2], plf[2];
#pragma unroll
    for (int ks = 0; ks < 2; ++ks) {
      phf[ks] = *(const short8*)&plh[l15][ks * 32 + grp * 8];
      plf[ks] = *(const short8*)&pll[l15][ks * 32 + grp * 8];
    }
#pragma unroll
    for (int dc = 0; dc < 8; ++dc) {
      const int dr = dc * 16 + l15;
      const int sw = dr & 7;
      f32x4 acc = oacc[dc];
#pragma unroll
      for (int ks = 0; ks < 2; ++ks) {
        const int voff = dr * 64 + ((((ks << 2) | grp) ^ sw) << 3);
        short8 vhf = *(const short8*)&vh[voff];
        short8 vlf = *(const short8*)&vl[voff];
        acc = __builtin_amdgcn_mfma_f32_16x16x32_bf16(vhf, phf[ks], acc, 0, 0, 0);
        acc = __builtin_amdgcn_mfma_f32_16x16x32_bf16(vlf, phf[ks], acc, 0, 0, 0);
        acc = __builtin_amdgcn_mfma_f32_16x16x32_bf16(vhf, plf[ks], acc, 0, 0, 0);
      }
      oacc[dc] = acc;
    }
    __syncthreads();
    cur ^= 1;
  }
  float inv = 1.0f / l_run;
#pragma unroll
  for (int dc = 0; dc < 8; ++dc)
#pragma unroll
    for (int rp = 0; rp < 2; ++rp) {
      float v0 = oacc[dc][rp * 2] * inv;
      float v1 = oacc[dc][rp * 2 + 1] * inv;
      u16 h0 = f2bf(v0), h1 = f2bf(v1);
      u16 lo0 = f2bf(v0 - bf2f(h0)), lo1 = f2bf(v1 - bf2f(h1));
      size_t o = (size_t)q_glob * 2048 + hh * 128 + dc * 16 + grp * 4 + rp * 2;
      *(unsigned*)&atth[o] = (unsigned)h0 | ((unsigned)h1 << 16);
      *(unsigned*)&attl[o] = (unsigned)lo0 | ((unsigned)lo1 << 16);
    }
}

// Router: f32 logits (exact top-2 selection); emits top-2 idx + normed weights.
__global__ __launch_bounds__(256) void k_router(const float* __restrict__ h2f,
                                                const float* __restrict__ gw,
                                                int2* __restrict__ tidx,
                                                float2* __restrict__ twgt) {
  const int tok = blockIdx.x;
  const float* hrow = h2f + (size_t)tok * 2048;
  float part[8];
#pragma unroll
  for (int e = 0; e < 8; ++e) part[e] = 0.f;
  for (int j = 0; j < 8; ++j) {
    int p = j * 256 + threadIdx.x;
    float hv = hrow[p];
#pragma unroll
    for (int e = 0; e < 8; ++e) part[e] += hv * gw[e * 2048 + p];
  }
#pragma unroll
  for (int e = 0; e < 8; ++e)
#pragma unroll
    for (int off = 32; off; off >>= 1) part[e] += __shfl_xor(part[e], off);
  __shared__ float red[4][8];
  int wv = threadIdx.x >> 6, lane = threadIdx.x & 63;
  if (lane == 0) {
#pragma unroll
    for (int e = 0; e < 8; ++e) red[wv][e] = part[e];
  }
  __syncthreads();
  if (threadIdx.x == 0) {
    float lg[8];
#pragma unroll
    for (int e = 0; e < 8; ++e) lg[e] = red[0][e] + red[1][e] + red[2][e] + red[3][e];
    float m = lg[0];
#pragma unroll
    for (int e = 1; e < 8; ++e) m = fmaxf(m, lg[e]);
    float ex[8], s = 0.f;
#pragma unroll
    for (int e = 0; e < 8; ++e) { ex[e] = expf(lg[e] - m); s += ex[e]; }
#pragma unroll
    for (int e = 0; e < 8; ++e) ex[e] /= s;
    int i1 = 0;
#pragma unroll
    for (int e = 1; e < 8; ++e) if (ex[e] > ex[i1]) i1 = e;
    int i2 = (i1 == 0) ? 1 : 0;
#pragma unroll
    for (int e = 0; e < 8; ++e) if (e != i1 && ex[e] > ex[i2]) i2 = e;
    float s2 = ex[i1] + ex[i2] + 1e-20f;
    tidx[tok] = make_int2(i1, i2);
    twgt[tok] = make_float2(ex[i1] / s2, ex[i2] / s2);
  }
}

// Deterministic token gather, single wave (race-free). See r3 comments.
__global__ __launch_bounds__(64) void k_scan(const int2* __restrict__ tidx,
                                             const float2* __restrict__ twgt,
                                             int* __restrict__ meta,
                                             int* __restrict__ toklist,
                                             float* __restrict__ slotw,
                                             int* __restrict__ slots) {
  const int lane = threadIdx.x;
  int base = 0;
  for (int e = 0; e < 8; ++e) {
    int cnt = 0;
    for (int c = 0; c < 16; ++c) {
      const int tok = c * 64 + lane;
      int2 my = tidx[tok];
      int f1 = (my.x == e), f2 = (my.y == e);
      int flag = f1 | f2;
      unsigned long long m = __ballot(flag);
      if (flag) {
        float2 w = twgt[tok];
        int rank = (int)__popcll(m & ((1ull << lane) - 1ull));
        int s = base + cnt + rank;
        toklist[s] = tok;
        slotw[s] = f1 ? w.x : w.y;
        slots[tok * 2 + (f1 ? 0 : 1)] = s;
      }
      cnt += (int)__popcll(m);
    }
    if (lane == 0) { meta[e] = base; meta[9 + e] = cnt; }
    const int padded = ((cnt + 127) >> 7) << 7;
    for (int s = cnt + lane; s < padded; s += 64) {
      toklist[base + s] = 0;
      slotw[base + s] = 0.f;
    }
    base += padded;
  }
  if (lane == 0) meta[8] = base;
}

// ---------------- GEMM kernels ----------------
// C[M,N] = A[M,K] @ B[N,K]^T. MFMA 16x16x32 bf16; C/D: col=lane&15,
// row=(lane>>4)*4+reg.

// Split GEMM, all-bf16 staging, 128x64 tile, BK=64, swizzled (r12).
__global__ __launch_bounds__(256) void k_gemm_bf16split(
    const u16* __restrict__ Ah, const u16* __restrict__ Al,
    const u16* __restrict__ Bh0, const u16* __restrict__ Bl0,
    const u16* __restrict__ Bh1, const u16* __restrict__ Bl1,
    const u16* __restrict__ Bh2, const u16* __restrict__ Bl2,
    float* __restrict__ C0, float* __restrict__ C1, float* __restrict__ C2,
    const float* __restrict__ resid) {
  __shared__ u16 lsAh[8192], lsAl[8192], lsBh[4096], lsBl[4096];  // 48KB
  const int z = blockIdx.z;
  const u16* Bh = (z == 0) ? Bh0 : (z == 1) ? Bh1 : Bh2;
  const u16* Bl = (z == 0) ? Bl0 : (z == 1) ? Bl1 : Bl2;
  float* Cm = (z == 0) ? C0 : (z == 1) ? C1 : C2;
  const int tid = threadIdx.x, lane = tid & 63, wv = tid >> 6;
  const int wr = (wv >> 1) * 64, wc = (wv & 1) * 32;
  const int fr = lane & 15, fg = lane >> 4;
  const int row0 = blockIdx.x * 128, col0 = blockIdx.y * 64;
  f32x4 acc[4][2];
#pragma unroll
  for (int i = 0; i < 4; ++i)
#pragma unroll
    for (int j = 0; j < 2; ++j) acc[i][j] = 0.f;

  size_t aoff[4], boff[2];
#pragma unroll
  for (int it = 0; it < 4; ++it) {
    const int eo = it * 2048 + wv * 512 + lane * 8;
    const int r = eo >> 6, g = (eo >> 3) & 7;
    aoff[it] = (size_t)(row0 + r) * 2048 + ((g ^ (r & 7)) << 3);
  }
#pragma unroll
  for (int it = 0; it < 2; ++it) {
    const int eo = it * 2048 + wv * 512 + lane * 8;
    const int r = eo >> 6, g = (eo >> 3) & 7;
    boff[it] = (size_t)(col0 + r) * 2048 + ((g ^ (r & 7)) << 3);
  }

  for (int kt = 0; kt < 32; ++kt) {
    const int k0 = kt * 64;
#pragma unroll
    for (int it = 0; it < 4; ++it) {
      const int ebase = it * 2048 + wv * 512;
      gload16(Ah + aoff[it] + k0, lsAh + ebase);
      gload16(Al + aoff[it] + k0, lsAl + ebase);
    }
#pragma unroll
    for (int it = 0; it < 2; ++it) {
      const int ebase = it * 2048 + wv * 512;
      gload16(Bh + boff[it] + k0, lsBh + ebase);
      gload16(Bl + boff[it] + k0, lsBl + ebase);
    }
    __syncthreads();
#pragma unroll
    for (int kk = 0; kk < 2; ++kk) {
      short8 ah[4], al[4], bh[2], bl[2];
#pragma unroll
      for (int mi = 0; mi < 4; ++mi) {
        const int row = wr + mi * 16 + fr;
        const int off = row * 64 + ((kk * 32 + fg * 8) ^ ((row & 7) << 3));
        ah[mi] = *(const short8*)&lsAh[off];
        al[mi] = *(const short8*)&lsAl[off];
      }
#pragma unroll
      for (int ni = 0; ni < 2; ++ni) {
        const int row = wc + ni * 16 + fr;
        const int off = row * 64 + ((kk * 32 + fg * 8) ^ ((row & 7) << 3));
        bh[ni] = *(const short8*)&lsBh[off];
        bl[ni] = *(const short8*)&lsBl[off];
      }
#pragma unroll
      for (int mi = 0; mi < 4; ++mi)
#pragma unroll
        for (int ni = 0; ni < 2; ++ni) {
          f32x4 c = acc[mi][ni];
          c = __builtin_amdgcn_mfma_f32_16x16x32_bf16(al[mi], bh[ni], c, 0, 0, 0);
          c = __builtin_amdgcn_mfma_f32_16x16x32_bf16(ah[mi], bl[ni], c, 0, 0, 0);
          c = __builtin_amdgcn_mfma_f32_16x16x32_bf16(ah[mi], bh[ni], c, 0, 0, 0);
          acc[mi][ni] = c;
        }
    }
    __syncthreads();
  }
  const bool hasres = (resid != nullptr);
#pragma unroll
  for (int mi = 0; mi < 4; ++mi)
#pragma unroll
    for (int ni = 0; ni < 2; ++ni)
#pragma unroll
      for (int qq = 0; qq < 4; ++qq) {
        const int row = row0 + wr + mi * 16 + fg * 4 + qq;
        const int col = col0 + wc + ni * 16 + fr;
        float val = acc[mi][ni][qq];
        if (hasres) val += resid[(size_t)row * 2048 + col];
        Cm[(size_t)row * 2048 + col] = val;
      }
}

// Find expert for a padded row-tile index. meta[0..8] = offsets (mult of 128).
DI int tile_to_expert(const int* meta, int t) {
  int e = 0;
  while (e < 7 && t >= (meta[e + 1] >> 7)) ++e;
  return e;
}

// Fused dual GEMM + SiLU, r11 1-phase BK=32 structure (EXACT revert: t-major
// order preserves per-expert B-panel L2 locality). Sparse (bid<528) + shared
// (bid>=528).
__global__ __launch_bounds__(256) void k_dual_all(
    const u16* __restrict__ h2b, const float* __restrict__ eg,
    const float* __restrict__ eu, const float* __restrict__ sg,
    const float* __restrict__ su, const int* __restrict__ meta,
    const int* __restrict__ toklist, const float* __restrict__ slotw,
    u16* __restrict__ act, u16* __restrict__ acts) {
  const int wid = blockIdx.x;
  const bool isShared = wid >= 528;
  __shared__ int toks[128];
  __shared__ u16 lsA[4096], lsG[2048], lsU[2048];  // 16.5KB
  const int tid = threadIdx.x, lane = tid & 63, wv = tid >> 6;
  const int wr = (wv >> 1) * 64, wc = (wv & 1) * 32;
  const int fr = lane & 15, fg = lane >> 4;

  int n0, off_e = 0, cnt_e = 0, rtile = 0;
  const float *Bg, *Bu;
  if (isShared) {
    const int b2 = wid - 528;
    rtile = b2 / 44;
    n0 = (b2 % 44) * 64;
    Bg = sg;
    Bu = su;
    if (tid < 128) toks[tid] = rtile * 128 + tid;
  } else {
    const int t = wid / 22;
    if (t >= (meta[8] >> 7)) return;
    n0 = (wid % 22) * 64;
    const int e = tile_to_expert(meta, t);
    off_e = meta[e];
    cnt_e = meta[9 + e];
    rtile = t - (off_e >> 7);
    Bg = eg + (size_t)e * 1408 * 2048;
    Bu = eu + (size_t)e * 1408 * 2048;
    if (tid < 128) toks[tid] = toklist[off_e + rtile * 128 + tid] & 1023;
  }
  f32x4 ag[4][2], au[4][2];
#pragma unroll
  for (int i = 0; i < 4; ++i)
#pragma unroll
    for (int j = 0; j < 2; ++j) { ag[i][j] = 0.f; au[i][j] = 0.f; }
  __syncthreads();  // toks visible

  // Hoisted per-thread base addresses.
  const int ebase0 = wv * 512, ebase1 = 2048 + wv * 512;
  const int eoA0 = ebase0 + lane * 8, eoA1 = ebase1 + lane * 8;
  const u16* aS0 = h2b + (size_t)toks[eoA0 >> 5] * 2048 + (eoA0 & 31);
  const u16* aS1 = h2b + (size_t)toks[eoA1 >> 5] * 2048 + (eoA1 & 31);
  const int eoB0 = tid * 4, eoB1 = (256 + tid) * 4;
  const float* gB0 = Bg + (size_t)(n0 + (eoB0 >> 5)) * 2048 + (eoB0 & 31);
  const float* gB1 = Bg + (size_t)(n0 + (eoB1 >> 5)) * 2048 + (eoB1 & 31);
  const float* uB0 = Bu + (size_t)(n0 + (eoB0 >> 5)) * 2048 + (eoB0 & 31);
  const float* uB1 = Bu + (size_t)(n0 + (eoB1 >> 5)) * 2048 + (eoB1 & 31);

  for (int kt = 0; kt < 64; ++kt) {
    const int k0 = kt * 32;
    gload16(aS0 + k0, lsA + ebase0);
    gload16(aS1 + k0, lsA + ebase1);
    float4 g0 = *(const float4*)(gB0 + k0);
    float4 g1 = *(const float4*)(gB1 + k0);
    float4 u0 = *(const float4*)(uB0 + k0);
    float4 u1 = *(const float4*)(uB1 + k0);
    *(unsigned*)&lsG[eoB0] = pack2(g0.x, g0.y);
    *(unsigned*)&lsG[eoB0 + 2] = pack2(g0.z, g0.w);
    *(unsigned*)&lsG[eoB1] = pack2(g1.x, g1.y);
    *(unsigned*)&lsG[eoB1 + 2] = pack2(g1.z, g1.w);
    *(unsigned*)&lsU[eoB0] = pack2(u0.x, u0.y);
    *(unsigned*)&lsU[eoB0 + 2] = pack2(u0.z, u0.w);
    *(unsigned*)&lsU[eoB1] = pack2(u1.x, u1.y);
    *(unsigned*)&lsU[eoB1 + 2] = pack2(u1.z, u1.w);
    __syncthreads();
    short8 af[4], gf[2], uf[2];
#pragma unroll
    for (int mi = 0; mi < 4; ++mi)
      af[mi] = *(const short8*)&lsA[(wr + mi * 16 + fr) * 32 + fg * 8];
#pragma unroll
    for (int ni = 0; ni < 2; ++ni) {
      const int off = (wc + ni * 16 + fr) * 32 + fg * 8;
      gf[ni] = *(const short8*)&lsG[off];
      uf[ni] = *(const short8*)&lsU[off];
    }
#pragma unroll
    for (int mi = 0; mi < 4; ++mi)
#pragma unroll
      for (int ni = 0; ni < 2; ++ni) {
        ag[mi][ni] = __builtin_amdgcn_mfma_f32_16x16x32_bf16(af[mi], gf[ni], ag[mi][ni], 0, 0, 0);
        au[mi][ni] = __builtin_amdgcn_mfma_f32_16x16x32_bf16(af[mi], uf[ni], au[mi][ni], 0, 0, 0);
      }
    __syncthreads();
  }
#pragma unroll
  for (int mi = 0; mi < 4; ++mi)
#pragma unroll
    for (int ni = 0; ni < 2; ++ni)
#pragma unroll
      for (int qq = 0; qq < 4; ++qq) {
        const int r = wr + mi * 16 + fg * 4 + qq;
        const int col = n0 + wc + ni * 16 + fr;
        float g = ag[mi][ni][qq], u = au[mi][ni][qq];
        float a = g / (1.0f + expf(-g)) * u;
        if (isShared) {
          acts[(size_t)(rtile * 128 + r) * 2816 + col] = f2bf(a);
        } else {
          const int rowInE = rtile * 128 + r;
          if (rowInE < cnt_e)
            act[(size_t)(off_e + rowInE) * 1408 + col] = f2bf(a * slotw[off_e + rowInE]);
        }
      }
}

// Fused down GEMMs, r12 structure (BK=64, swizzled). Sparse (wid<384 -> dwn)
// + shared (wid>=384 -> shd).
__global__ __launch_bounds__(256) void k_down_all(
    const u16* __restrict__ act, const float* __restrict__ ed,
    const u16* __restrict__ acts, const float* __restrict__ sd,
    const int* __restrict__ meta, float* __restrict__ dwn,
    float* __restrict__ shd) {
  __shared__ u16 lsA[8192], lsB[8192];  // 32KB
  const int wid = blockIdx.x;
  const int tid = threadIdx.x, lane = tid & 63, wv = tid >> 6;
  const int fr = lane & 15, fg = lane >> 4;
  if (wid < 384) {
    const int t = wid >> 4;
    if (t >= (meta[8] >> 7)) return;
    const int col0 = (wid & 15) * 128;
    const int e = tile_to_expert(meta, t);
    const int off_e = meta[e];
    const int rtile = t - (off_e >> 7);
    const int wr = (wv >> 1) * 64, wc = (wv & 1) * 64;
    const u16* Ab = act + (size_t)off_e * 1408;
    const float* Bb = ed + (size_t)e * 2048 * 1408;
    const u16* aS[4];
#pragma unroll
    for (int it = 0; it < 4; ++it) {
      const int eo = it * 2048 + wv * 512 + lane * 8;
      const int r = eo >> 6, g = (eo >> 3) & 7;
      aS[it] = Ab + (size_t)(rtile * 128 + r) * 1408 + ((g ^ (r & 7)) << 3);
    }
    const float* bB[8];
    int sB[8];
#pragma unroll
    for (int j = 0; j < 8; ++j) {
      const int eo = (j * 256 + tid) * 4;
      const int row = eo >> 6, colu = eo & 63;
      sB[j] = row * 64 + (colu ^ ((row & 7) << 3));
      bB[j] = Bb + (size_t)(col0 + row) * 1408 + colu;
    }
    f32x4 acc[4][4];
#pragma unroll
    for (int i = 0; i < 4; ++i)
#pragma unroll
      for (int j = 0; j < 4; ++j) acc[i][j] = 0.f;
    for (int kt = 0; kt < 22; ++kt) {
      const int k0 = kt * 64;
#pragma unroll
      for (int it = 0; it < 4; ++it)
        gload16(aS[it] + k0, lsA + it * 2048 + wv * 512);
#pragma unroll
      for (int j = 0; j < 8; ++j) {
        float4 b = *(const float4*)(bB[j] + k0);
        *(unsigned*)&lsB[sB[j]] = pack2(b.x, b.y);
        *(unsigned*)&lsB[sB[j] + 2] = pack2(b.z, b.w);
      }
      __syncthreads();
#pragma unroll
      for (int kk = 0; kk < 2; ++kk) {
        short8 af[4], bf_[4];
#pragma unroll
        for (int mi = 0; mi < 4; ++mi) {
          const int row = wr + mi * 16 + fr;
          af[mi] = *(const short8*)&lsA[row * 64 + ((kk * 32 + fg * 8) ^ ((row & 7) << 3))];
        }
#pragma unroll
        for (int ni = 0; ni < 4; ++ni) {
          const int row = wc + ni * 16 + fr;
          bf_[ni] = *(const short8*)&lsB[row * 64 + ((kk * 32 + fg * 8) ^ ((row & 7) << 3))];
        }
#pragma unroll
        for (int mi = 0; mi < 4; ++mi)
#pragma unroll
          for (int ni = 0; ni < 4; ++ni)
            acc[mi][ni] = __builtin_amdgcn_mfma_f32_16x16x32_bf16(af[mi], bf_[ni], acc[mi][ni], 0, 0, 0);
      }
      __syncthreads();
    }
#pragma unroll
    for (int mi = 0; mi < 4; ++mi)
#pragma unroll
      for (int ni = 0; ni < 4; ++ni)
#pragma unroll
        for (int qq = 0; qq < 4; ++qq) {
          const int r = wr + mi * 16 + fg * 4 + qq;
          const int col = col0 + wc + ni * 16 + fr;
          dwn[(size_t)(off_e + rtile * 128 + r) * 2048 + col] = acc[mi][ni][qq];
        }
  } else {
    const int b2 = wid - 384;
    const int row0 = (b2 >> 5) * 128;
    const int col0 = (b2 & 31) * 64;
    const int wr = (wv >> 1) * 64, wc = (wv & 1) * 32;
    const u16* aS[4];
#pragma unroll
    for (int it = 0; it < 4; ++it) {
      const int eo = it * 2048 + wv * 512 + lane * 8;
      const int r = eo >> 6, g = (eo >> 3) & 7;
      aS[it] = acts + (size_t)(row0 + r) * 2816 + ((g ^ (r & 7)) << 3);
    }
    const float* bB[4];
    int sB[4];
#pragma unroll
    for (int j = 0; j < 4; ++j) {
      const int eo = (j * 256 + tid) * 4;
      const int row = eo >> 6, colu = eo & 63;
      sB[j] = row * 64 + (colu ^ ((row & 7) << 3));
      bB[j] = sd + (size_t)(col0 + row) * 2816 + colu;
    }
    f32x4 acc[4][2];
#pragma unroll
    for (int i = 0; i < 4; ++i)
#pragma unroll
      for (int j = 0; j < 2; ++j) acc[i][j] = 0.f;
    for (int kt = 0; kt < 44; ++kt) {
      const int k0 = kt * 64;
#pragma unroll
      for (int it = 0; it < 4; ++it)
        gload16(aS[it] + k0, lsA + it * 2048 + wv * 512);
#pragma unroll
      for (int j = 0; j < 4; ++j) {
        float4 b = *(const float4*)(bB[j] + k0);
        *(unsigned*)&lsB[sB[j]] = pack2(b.x, b.y);
        *(unsigned*)&lsB[sB[j] + 2] = pack2(b.z, b.w);
      }
      __syncthreads();
#pragma unroll
      for (int kk = 0; kk < 2; ++kk) {
        short8 af[4], bf_[2];
#pragma unroll
        for (int mi = 0; mi < 4; ++mi) {
          const int row = wr + mi * 16 + fr;
          af[mi] = *(const short8*)&lsA[row * 64 + ((kk * 32 + fg * 8) ^ ((row & 7) << 3))];
        }
#pragma unroll
        for (int ni = 0; ni < 2; ++ni) {
          const int row = wc + ni * 16 + fr;
          bf_[ni] = *(const short8*)&lsB[row * 64 + ((kk * 32 + fg * 8) ^ ((row & 7) << 3))];
        }
#pragma unroll
        for (int mi = 0; mi < 4; ++mi)
#pragma unroll
          for (int ni = 0; ni < 2; ++ni)
            acc[mi][ni] = __builtin_amdgcn_mfma_f32_16x16x32_bf16(af[mi], bf_[ni], acc[mi][ni], 0, 0, 0);
      }
      __syncthreads();
    }
#pragma unroll
    for (int mi = 0; mi < 4; ++mi)
#pragma unroll
      for (int ni = 0; ni < 2; ++ni)
#pragma unroll
        for (int qq = 0; qq < 4; ++qq) {
          const int row = row0 + wr + mi * 16 + fg * 4 + qq;
          const int col = col0 + wc + ni * 16 + fr;
          shd[(size_t)row * 2048 + col] = acc[mi][ni][qq];
        }
  }
}

// Final combine: out = x + shd + dwn[slot0] + dwn[slot1].
__global__ __launch_bounds__(256) void k_combine(
    const float* __restrict__ shd, const float* __restrict__ x,
    const float* __restrict__ dwn, const int* __restrict__ slots,
    float* __restrict__ outp) {
  const int i4 = (blockIdx.x * 256 + threadIdx.x) * 4;
  const int row = i4 >> 11, col = i4 & 2047;
  const int s0 = slots[row * 2], s1 = slots[row * 2 + 1];
  float4 a = *(const float4*)&shd[i4];
  float4 b = *(const float4*)&x[i4];
  float4 c = *(const float4*)&dwn[(size_t)s0 * 2048 + col];
  float4 d = *(const float4*)&dwn[(size_t)s1 * 2048 + col];
  float4 o;
  o.x = a.x + b.x + c.x + d.x;
  o.y = a.y + b.y + c.y + d.y;
  o.z = a.z + b.z + c.z + d.z;
  o.w = a.w + b.w + c.w + d.w;
  *(float4*)&outp[i4] = o;
}

// ---------------- host launch ----------------

extern "C" void kernel_launch(void* const* d_in, const int* in_sizes, int n_in,
                              void* d_out, int out_size, void* d_ws, size_t ws_size,
                              hipStream_t stream) {
  (void)in_sizes; (void)n_in; (void)out_size; (void)ws_size;
  const float* hidden = (const float*)d_in[0];
  const float* ln1 = (const float*)d_in[1];
  const float* ln2 = (const float*)d_in[2];
  const float* wq = (const float*)d_in[3];
  const float* wk = (const float*)d_in[4];
  const float* wvw = (const float*)d_in[5];
  const float* wo = (const float*)d_in[6];
  const float* gw = (const float*)d_in[7];
  const float* eg = (const float*)d_in[8];
  const float* eu = (const float*)d_in[9];
  const float* ed = (const float*)d_in[10];
  const float* sg = (const float*)d_in[11];
  const float* su = (const float*)d_in[12];
  const float* sd = (const float*)d_in[13];
  float* out = (float*)d_out;
  char* ws = (char*)d_ws;

  const size_t KB = 1ull << 10, MB = 1ull << 20;
  float* tab = (float*)(ws + 0);             // [0, 0.5MB)
  int2* tidx = (int2*)(ws + 512 * KB);
  float2* twgt = (float2*)(ws + 520 * KB);
  int* meta = (int*)(ws + 528 * KB);
  int* tokl = (int*)(ws + 532 * KB);
  float* slw = (float*)(ws + 544 * KB);
  int* slots = (int*)(ws + 556 * KB);
  u16* hnh = (u16*)(ws + 1 * MB);            // [1,5)   dies after QKV
  u16* hnl = (u16*)(ws + 5 * MB);            // [5,9)
  u16* wqh = (u16*)(ws + 9 * MB);            // [9,57): split wq/wk/wv, die after QKV
  u16* wql = (u16*)(ws + 17 * MB);
  u16* wkh = (u16*)(ws + 25 * MB);
  u16* wkl = (u16*)(ws + 33 * MB);
  u16* wvh = (u16*)(ws + 41 * MB);
  u16* wvl = (u16*)(ws + 49 * MB);
  u16* woh = (u16*)(ws + 57 * MB);           // [57,73): dies after O-proj
  u16* wol = (u16*)(ws + 65 * MB);
  float* qf = (float*)(ws + 73 * MB);        // [73,81) dies after ropesplit
  float* kf = (float*)(ws + 81 * MB);        // [81,89)
  float* vf = (float*)(ws + 89 * MB);        // [89,97)
  // After QKV GEMM (wq..wvl dead):
  u16* Qh = (u16*)(ws + 9 * MB);             // [9,33): attn operands
  u16* Ql = (u16*)(ws + 13 * MB);
  u16* Kh = (u16*)(ws + 17 * MB);
  u16* Kl = (u16*)(ws + 21 * MB);
  u16* Vth = (u16*)(ws + 25 * MB);
  u16* Vtl = (u16*)(ws + 29 * MB);
  u16* atth = (u16*)(ws + 33 * MB);          // [33,41): dies after O-proj
  u16* attl = (u16*)(ws + 37 * MB);
  float* xf = (float*)(ws + 41 * MB);        // [41,49): residual2 (live to end)
  float* h2f = (float*)(ws + 49 * MB);       // [49,57)
  u16* h2b = (u16*)(ws + 1 * MB);            // [1,5) (hnh dead)
  // MoE (after attn; Qh..Vtl / qf..vf / atth dead):
  u16* act = (u16*)(ws + 73 * MB);           // [73,82)  3072x1408 bf16
  u16* acts = (u16*)(ws + 82 * MB);          // [82,88)  1024x2816 bf16
  float* dwn = (float*)(ws + 9 * MB);        // [9,33)   3072x2048 f32
  float* shd = (float*)(ws + 33 * MB);       // [33,41)  1024x2048 f32

  k_ropetab<<<256, 256, 0, stream>>>(tab);
  k_rmsnorm<<<1024, 256, 0, stream>>>(hidden, ln1, nullptr, hnh, hnl);
  k_splitf4<<<16384, 256, 0, stream>>>(wq, wk, wvw, wo, wqh, wkh, wvh, woh,
                                       wql, wkl, wvl, wol);
  k_gemm_bf16split<<<dim3(8, 32, 3), 256, 0, stream>>>(
      hnh, hnl, wqh, wql, wkh, wkl, wvh, wvl, qf, kf, vf, nullptr);
  k_ropesplit<<<1024, 256, 0, stream>>>(qf, kf, tab, Qh, Ql, Kh, Kl);
  k_splitv<<<2048, 256, 0, stream>>>(vf, Vth, Vtl);
  k_attn_tile<<<dim3(16, 16), 256, 0, stream>>>(Qh, Ql, Kh, Kl, Vth, Vtl, atth, attl);
  k_gemm_bf16split<<<dim3(8, 32, 1), 256, 0, stream>>>(
      atth, attl, woh, wol, woh, wol, woh, wol, xf, xf, xf, hidden);
  k_rmsnorm<<<1024, 256, 0, stream>>>(xf, ln2, h2f, h2b, nullptr);
  k_router<<<1024, 256, 0, stream>>>(h2f, gw, tidx, twgt);
  k_scan<<<1, 64, 0, stream>>>(tidx, twgt, meta, tokl, slw, slots);
  k_dual_all<<<880, 256, 0, stream>>>(h2b, eg, eu, sg, su, meta, tokl, slw, act, acts);
  k_down_all<<<640, 256, 0, stream>>>(act, ed, acts, sd, meta, dwn, shd);
  k_combine<<<2048, 256, 0, stream>>>(shd, xf, dwn, slots, out);
}